// Round 1
// baseline (2385.639 us; speedup 1.0000x reference)
//
#include <hip/hip_runtime.h>
#include <stdint.h>

// ============================================================================
// S2S2S LSTM forecaster, MI355X.
// Structure:
//   init_kernel     : zero d_out + h/c state in ws
//   xproj_kernel<D> : xt @ Wih^T + b for all t, bf16, MFMA-fragment-permuted
//                     layout in ws (parallel over B*T, full chip)
//   rec_kernel      : 16 blocks x 256 thr (1 block/CU, 1 wave/SIMD, 512 VGPR
//                     budget). Whh bf16 resident: 94 frags/wave in VGPR +
//                     34 frags/wave in LDS. h double-buffered in LDS, c in
//                     registers. Gate order i,f,g,o (PyTorch).
// Output: cols 0..75 = future-decoder head (out_f is overwritten by ref),
//         cols 76..90 = 0.
// ============================================================================

typedef __attribute__((ext_vector_type(8))) short short8;  // 8 x bf16
typedef __attribute__((ext_vector_type(4))) float f32x4;   // MFMA acc
typedef __attribute__((ext_vector_type(2))) unsigned int u32x2;

#define L2E 1.4426950408889634f
#define F_REG 94   // Whh frags per wave held in VGPRs
#define F_LDS 34   // Whh frags per wave held in LDS

__device__ __forceinline__ uint16_t f2bf(float f) {  // fp32 -> bf16 bits, RNE
  uint32_t x = __float_as_uint(f);
  x += 0x7fffu + ((x >> 16) & 1u);
  return (uint16_t)(x >> 16);
}
__device__ __forceinline__ uint32_t pk2(float a, float b) {
  return (uint32_t)f2bf(a) | ((uint32_t)f2bf(b) << 16);
}
__device__ __forceinline__ float bfhalf(uint32_t w, int hi) {  // bf16 -> fp32
  return __uint_as_float(hi ? (w & 0xffff0000u) : (w << 16));
}
__device__ __forceinline__ f32x4 MFMA(short8 a, short8 b, f32x4 c) {
  return __builtin_amdgcn_mfma_f32_16x16x32_bf16(a, b, c, 0, 0, 0);
}
__device__ __forceinline__ float ex2(float x) { return __builtin_amdgcn_exp2f(x); }
__device__ __forceinline__ float rcp(float x) { return __builtin_amdgcn_rcpf(x); }

// ---------------------------------------------------------------------------
__global__ void init_kernel(float* c_state, uint16_t* h_state, float* out) {
  int i = blockIdx.x * 256 + threadIdx.x;
  if (i < 65536) { c_state[i] = 0.f; h_state[i] = 0; }
  if (i < 256 * 91) out[i] = 0.f;
}

// ---------------------------------------------------------------------------
// xproj: out[t][b][n] = sum_k x[b][t][k]*Wih[n][k] + bias[n], stored bf16 in
// fragment-permuted layout: xp[(t-t0)][btile][nt][lane][j], j=0..3 matching
// the MFMA C/D map (row=(l>>4)*4+j, col=l&15). Block = 512 thr = 8 waves,
// handles one t and 8 batch-tiles; wave w covers n-tiles w*8..w*8+7.
// ---------------------------------------------------------------------------
template <int DIN>
__global__ __launch_bounds__(512) void xproj_kernel(
    const float* __restrict__ x, const float* __restrict__ Wih,
    const float* __restrict__ bias, uint32_t* __restrict__ xp,
    int t0, int T) {
  const int tid = threadIdx.x, w = tid >> 6, l = tid & 63;
  const int l16 = l & 15, lg = l >> 4;
  const int tc = blockIdx.x >> 1;          // chunk-local t
  const int sub = blockIdx.x & 1;          // which 8 batch-tiles
  const int t = t0 + tc;
  constexpr int KT = (DIN + 31) / 32;

  // B fragments (Wih) for this wave's 8 n-tiles
  short8 bfr[8][KT];
  float bv[8];
#pragma unroll
  for (int ni = 0; ni < 8; ++ni) {
    const int n = (w * 8 + ni) * 16 + l16;
    bv[ni] = bias[n];
#pragma unroll
    for (int kt = 0; kt < KT; ++kt) {
      const int k0 = kt * 32 + lg * 8;
      short8 fr;
#pragma unroll
      for (int e = 0; e < 8; ++e) fr[e] = 0;
      if (k0 + 8 <= DIN) {
        const float* s = Wih + (size_t)n * DIN + k0;
#pragma unroll
        for (int e = 0; e < 8; ++e) fr[e] = (short)f2bf(s[e]);
      }
      bfr[ni][kt] = fr;
    }
  }

  for (int mi = 0; mi < 8; ++mi) {
    const int btile = sub * 8 + mi;
    const int b = btile * 16 + l16;
    short8 af[KT];
#pragma unroll
    for (int kt = 0; kt < KT; ++kt) {
      const int k0 = kt * 32 + lg * 8;
      short8 fr;
#pragma unroll
      for (int e = 0; e < 8; ++e) fr[e] = 0;
      if (k0 + 8 <= DIN) {
        const float* s = x + ((size_t)b * T + t) * DIN + k0;
#pragma unroll
        for (int e = 0; e < 8; ++e) fr[e] = (short)f2bf(s[e]);
      }
      af[kt] = fr;
    }
#pragma unroll
    for (int ni = 0; ni < 8; ++ni) {
      f32x4 acc = {0.f, 0.f, 0.f, 0.f};
#pragma unroll
      for (int kt = 0; kt < KT; ++kt) acc = MFMA(af[kt], bfr[ni][kt], acc);
      const int nt = w * 8 + ni;
      size_t idx = ((((size_t)tc * 16 + btile) * 64 + nt) * 64 + l) * 2;
      u32x2 v;
      v[0] = pk2(acc[0] + bv[ni], acc[1] + bv[ni]);
      v[1] = pk2(acc[2] + bv[ni], acc[3] + bv[ni]);
      *(u32x2*)(xp + idx) = v;
    }
  }
}

// ---------------------------------------------------------------------------
// Recurrent kernel: one launch per (phase, chunk). 16 blocks, 256 threads.
// Wave w owns h-cols [64w, 64w+64); per lane: 4 batch rows x 4 hc (via p).
// n-tile for (gate g, sub p) = g*16 + w*4 + p.
// ---------------------------------------------------------------------------
__global__ __launch_bounds__(256, 1) void rec_kernel(
    const uint32_t* __restrict__ xp, const float* __restrict__ Whh,
    float* __restrict__ c_state, uint16_t* __restrict__ h_state,
    float* __restrict__ out, const float* __restrict__ headW,
    const float* __restrict__ headb, int ct, int tcol0, int do_head) {
  __shared__ short8 B_lds[4 * F_LDS * 64];   // 139264 B
  __shared__ uint16_t h_lds[2][16][264];     // 16896 B (pad 264 -> <=2-way)
  __shared__ float headbuf[16][64];          // 4096 B   (total 160256 B)

  const int tid = threadIdx.x, w = tid >> 6, l = tid & 63;
  const int l16 = l & 15, lg = l >> 4;
  const int blk = blockIdx.x, b0 = blk * 16;

  // ---- Whh -> bf16 fragments: regs + LDS (one-time) ----
  short8 breg[F_REG];
#pragma unroll
  for (int g = 0; g < 4; ++g)
#pragma unroll
    for (int p = 0; p < 4; ++p)
#pragma unroll
      for (int kt = 0; kt < 8; ++kt) {
        const int fl = (g * 4 + p) * 8 + kt;
        const int nt = g * 16 + w * 4 + p;
        const float* s = Whh + (size_t)(nt * 16 + l16) * 256 + kt * 32 + lg * 8;
        short8 fr;
#pragma unroll
        for (int e = 0; e < 8; ++e) fr[e] = (short)f2bf(s[e]);
        if (fl < F_REG) breg[fl] = fr;
        else B_lds[(w * F_LDS + (fl - F_REG)) * 64 + l] = fr;
      }

  // ---- state load ----
  float c_reg[4][4];
#pragma unroll
  for (int p = 0; p < 4; ++p)
#pragma unroll
    for (int j = 0; j < 4; ++j)
      c_reg[p][j] = c_state[(size_t)(b0 + lg * 4 + j) * 256 + w * 64 + p * 16 + l16];
  for (int idx = tid; idx < 16 * 256; idx += 256)
    h_lds[0][idx >> 8][idx & 255] = h_state[(size_t)(b0 + (idx >> 8)) * 256 + (idx & 255)];
  float hw[4];
#pragma unroll
  for (int p = 0; p < 4; ++p) hw[p] = headW[w * 64 + p * 16 + l16];
  const float hb = headb[0];

  // ---- xproj prefetch for t=0 ----
  u32x2 xpf[4][4];
#pragma unroll
  for (int g = 0; g < 4; ++g)
#pragma unroll
    for (int p = 0; p < 4; ++p) {
      size_t idx = ((((size_t)0 * 16 + blk) * 64 + (g * 16 + w * 4 + p)) * 64 + l) * 2;
      xpf[g][p] = *(const u32x2*)(xp + idx);
    }

  __syncthreads();

  for (int t = 0; t < ct; ++t) {
    const int cur = t & 1, nxt = cur ^ 1;
    const int tn = (t + 1 < ct) ? t + 1 : t;  // clamped prefetch target
    float hp[4] = {0.f, 0.f, 0.f, 0.f};

#pragma unroll
    for (int p = 0; p < 4; ++p) {
      f32x4 acc[4];
#pragma unroll
      for (int g = 0; g < 4; ++g) acc[g] = f32x4{0.f, 0.f, 0.f, 0.f};
#pragma unroll
      for (int kt = 0; kt < 8; ++kt) {
        short8 a = *(const short8*)(&h_lds[cur][l16][kt * 32 + lg * 8]);
#pragma unroll
        for (int g = 0; g < 4; ++g) {
          const int fl = (g * 4 + p) * 8 + kt;
          short8 bb;
          if (fl < F_REG) bb = breg[fl];
          else bb = B_lds[(w * F_LDS + (fl - F_REG)) * 64 + l];
          acc[g] = MFMA(a, bb, acc[g]);
        }
      }
      // ---- activations (all lane-local), i,f,g,o ----
#pragma unroll
      for (int j = 0; j < 4; ++j) {
        const int hi = j & 1, wd = j >> 1;
        float gi = acc[0][j] + bfhalf(xpf[0][p][wd], hi);
        float gf = acc[1][j] + bfhalf(xpf[1][p][wd], hi);
        float gg = acc[2][j] + bfhalf(xpf[2][p][wd], hi);
        float go = acc[3][j] + bfhalf(xpf[3][p][wd], hi);
        // sig(i)*tanh(g) = (eg-1) / ((1+ei)*(eg+1))
        float ei = ex2(-gi * L2E);
        float eg = ex2(fminf(2.f * gg * L2E, 80.f));
        float sitg = (eg - 1.f) * rcp((1.f + ei) * (eg + 1.f));
        float ef = ex2(-gf * L2E);
        float cc = fmaf(c_reg[p][j], rcp(1.f + ef), sitg);
        c_reg[p][j] = cc;
        float eo = ex2(-go * L2E);
        float ec = ex2(fminf(2.f * cc * L2E, 80.f));
        float hh = (ec - 1.f) * rcp((1.f + eo) * (ec + 1.f));
        hp[j] = fmaf(hh, hw[p], hp[j]);
        h_lds[nxt][lg * 4 + j][w * 64 + p * 16 + l16] = f2bf(hh);
      }
      // consume-then-prefetch next step's xproj for this p (hidden latency)
#pragma unroll
      for (int g = 0; g < 4; ++g) {
        size_t idx = ((((size_t)tn * 16 + blk) * 64 + (g * 16 + w * 4 + p)) * 64 + l) * 2;
        xpf[g][p] = *(const u32x2*)(xp + idx);
      }
    }

    if (do_head) {
#pragma unroll
      for (int j = 0; j < 4; ++j) headbuf[lg * 4 + j][w * 16 + l16] = hp[j];
      __syncthreads();
      {
        const int b = tid >> 4, i = tid & 15;
        float s = headbuf[b][i] + headbuf[b][16 + i] + headbuf[b][32 + i] + headbuf[b][48 + i];
        s += __shfl_down(s, 8, 16);
        s += __shfl_down(s, 4, 16);
        s += __shfl_down(s, 2, 16);
        s += __shfl_down(s, 1, 16);
        if (i == 0) out[(size_t)(b0 + b) * 91 + (tcol0 + t)] = s + hb;
      }
      __syncthreads();  // headbuf reuse + h_lds[nxt] ready
    } else {
      __syncthreads();
    }
  }

  // ---- state writeback ----
#pragma unroll
  for (int p = 0; p < 4; ++p)
#pragma unroll
    for (int j = 0; j < 4; ++j)
      c_state[(size_t)(b0 + lg * 4 + j) * 256 + w * 64 + p * 16 + l16] = c_reg[p][j];
  for (int idx = tid; idx < 16 * 256; idx += 256)
    h_state[(size_t)(b0 + (idx >> 8)) * 256 + (idx & 255)] = h_lds[ct & 1][idx >> 8][idx & 255];
}

// ---------------------------------------------------------------------------
extern "C" void kernel_launch(void* const* d_in, const int* in_sizes, int n_in,
                              void* d_out, int out_size, void* d_ws, size_t ws_size,
                              hipStream_t stream) {
  const float* headW = (const float*)d_in[12];
  const float* headb = (const float*)d_in[13];
  float* out = (float*)d_out;

  char* ws = (char*)d_ws;
  float* c_state = (float*)ws;                      // 256 KB
  uint16_t* h_state = (uint16_t*)(ws + 262144);     // 128 KB
  uint32_t* xp = (uint32_t*)(ws + 393216);          // chunk buffer, 512 KB per t

  int ct_max = 1;
  if (ws_size > 393216 + 512 * 1024) {
    size_t c = (ws_size - 393216) / (512 * 1024);
    ct_max = (c > 365) ? 365 : (int)c;
  }

  init_kernel<<<256, 256, 0, stream>>>(c_state, h_state, out);

  struct Phase { const float* x; const float* Wih; const float* Whh; const float* b; int T; int D; int head; };
  Phase ph[3] = {
      {(const float*)d_in[0], (const float*)d_in[3], (const float*)d_in[4], (const float*)d_in[5],
       in_sizes[0] / (256 * 64), 64, 0},
      {(const float*)d_in[1], (const float*)d_in[6], (const float*)d_in[7], (const float*)d_in[8],
       in_sizes[1] / (256 * 32), 32, 0},
      {(const float*)d_in[2], (const float*)d_in[9], (const float*)d_in[10], (const float*)d_in[11],
       in_sizes[2] / (256 * 16), 16, 1},
  };

  for (int pi = 0; pi < 3; ++pi) {
    const Phase& P = ph[pi];
    for (int t0 = 0; t0 < P.T; t0 += ct_max) {
      int ct = (P.T - t0 < ct_max) ? (P.T - t0) : ct_max;
      dim3 g(ct * 2);
      if (P.D == 64)
        xproj_kernel<64><<<g, 512, 0, stream>>>(P.x, P.Wih, P.b, xp, t0, P.T);
      else if (P.D == 32)
        xproj_kernel<32><<<g, 512, 0, stream>>>(P.x, P.Wih, P.b, xp, t0, P.T);
      else
        xproj_kernel<16><<<g, 512, 0, stream>>>(P.x, P.Wih, P.b, xp, t0, P.T);
      rec_kernel<<<16, 256, 0, stream>>>(xp, P.Whh, c_state, h_state, out,
                                         headW, headb, ct, t0, P.head);
    }
  }
}

// Round 3
// 2206.684 us; speedup vs baseline: 1.0811x; 1.0811x over previous
//
#include <hip/hip_runtime.h>
#include <stdint.h>

// ============================================================================
// S2S2S LSTM forecaster, MI355X.  Round 3 = round-1 kernel (passed, absmax
// 1.95e-3) with ONE change: Whh fragments split 30 VGPR / 64 AGPR / 34 LDS
// instead of 94 VGPR (spilled) / 34 LDS. AGPR frags consumed via inline-asm
// v_mfma with "a" srcB; asm MFMAs only mid-chain (D->srcC), builtins open and
// close each chain so the compiler manages VALU<->MFMA hazards.
// ============================================================================

typedef __attribute__((ext_vector_type(8))) short short8;  // 8 x bf16
typedef __attribute__((ext_vector_type(4))) float f32x4;   // MFMA acc
typedef __attribute__((ext_vector_type(2))) unsigned int u32x2;

#define L2E 1.4426950408889634f

__device__ __forceinline__ uint16_t f2bf(float f) {  // fp32 -> bf16 bits, RNE
  uint32_t x = __float_as_uint(f);
  x += 0x7fffu + ((x >> 16) & 1u);
  return (uint16_t)(x >> 16);
}
__device__ __forceinline__ uint32_t pk2(float a, float b) {
  return (uint32_t)f2bf(a) | ((uint32_t)f2bf(b) << 16);
}
__device__ __forceinline__ float bfhalf(uint32_t w, int hi) {  // bf16 -> fp32
  return __uint_as_float(hi ? (w & 0xffff0000u) : (w << 16));
}
__device__ __forceinline__ f32x4 MFMA(short8 a, short8 b, f32x4 c) {
  return __builtin_amdgcn_mfma_f32_16x16x32_bf16(a, b, c, 0, 0, 0);
}
// MFMA with B operand pinned in AGPRs. Only used mid-chain (srcC comes from a
// previous MFMA, D feeds the next MFMA's srcC) -> no manual wait states.
__device__ __forceinline__ f32x4 mfma_a(short8 a, short8 b, f32x4 c) {
  asm("v_mfma_f32_16x16x32_bf16 %0, %1, %2, %0" : "+v"(c) : "v"(a), "a"(b));
  return c;
}
__device__ __forceinline__ float ex2(float x) { return __builtin_amdgcn_exp2f(x); }
__device__ __forceinline__ float rcp(float x) { return __builtin_amdgcn_rcpf(x); }

// ---------------------------------------------------------------------------
__global__ void init_kernel(float* c_state, uint16_t* h_state, float* out) {
  int i = blockIdx.x * 256 + threadIdx.x;
  if (i < 65536) { c_state[i] = 0.f; h_state[i] = 0; }
  if (i < 256 * 91) out[i] = 0.f;
}

// ---------------------------------------------------------------------------
// xproj: out[t][b][n] = sum_k x[b][t][k]*Wih[n][k] + bias[n], stored bf16 in
// fragment-permuted layout: xp[(t-t0)][btile][nt][lane][j] matching the MFMA
// C/D map (row=(l>>4)*4+j, col=l&15). Block = 512 thr = 8 waves.
// ---------------------------------------------------------------------------
template <int DIN>
__global__ __launch_bounds__(512) void xproj_kernel(
    const float* __restrict__ x, const float* __restrict__ Wih,
    const float* __restrict__ bias, uint32_t* __restrict__ xp,
    int t0, int T) {
  const int tid = threadIdx.x, w = tid >> 6, l = tid & 63;
  const int l16 = l & 15, lg = l >> 4;
  const int tc = blockIdx.x >> 1;          // chunk-local t
  const int sub = blockIdx.x & 1;          // which 8 batch-tiles
  const int t = t0 + tc;
  constexpr int KT = (DIN + 31) / 32;

  short8 bfr[8][KT];
  float bv[8];
#pragma unroll
  for (int ni = 0; ni < 8; ++ni) {
    const int n = (w * 8 + ni) * 16 + l16;
    bv[ni] = bias[n];
#pragma unroll
    for (int kt = 0; kt < KT; ++kt) {
      const int k0 = kt * 32 + lg * 8;
      short8 fr;
#pragma unroll
      for (int e = 0; e < 8; ++e) fr[e] = 0;
      if (k0 + 8 <= DIN) {
        const float* s = Wih + (size_t)n * DIN + k0;
#pragma unroll
        for (int e = 0; e < 8; ++e) fr[e] = (short)f2bf(s[e]);
      }
      bfr[ni][kt] = fr;
    }
  }

  for (int mi = 0; mi < 8; ++mi) {
    const int btile = sub * 8 + mi;
    const int b = btile * 16 + l16;
    short8 af[KT];
#pragma unroll
    for (int kt = 0; kt < KT; ++kt) {
      const int k0 = kt * 32 + lg * 8;
      short8 fr;
#pragma unroll
      for (int e = 0; e < 8; ++e) fr[e] = 0;
      if (k0 + 8 <= DIN) {
        const float* s = x + ((size_t)b * T + t) * DIN + k0;
#pragma unroll
        for (int e = 0; e < 8; ++e) fr[e] = (short)f2bf(s[e]);
      }
      af[kt] = fr;
    }
#pragma unroll
    for (int ni = 0; ni < 8; ++ni) {
      f32x4 acc = {0.f, 0.f, 0.f, 0.f};
#pragma unroll
      for (int kt = 0; kt < KT; ++kt) acc = MFMA(af[kt], bfr[ni][kt], acc);
      const int nt = w * 8 + ni;
      size_t idx = ((((size_t)tc * 16 + btile) * 64 + nt) * 64 + l) * 2;
      u32x2 v;
      v[0] = pk2(acc[0] + bv[ni], acc[1] + bv[ni]);
      v[1] = pk2(acc[2] + bv[ni], acc[3] + bv[ni]);
      *(u32x2*)(xp + idx) = v;
    }
  }
}

// ---------------------------------------------------------------------------
// Recurrent kernel: 16 blocks x 256 thr (1 block/CU, 1 wave/SIMD).
// Wave w owns h-cols [64w, 64w+64); per lane: 4 batch rows x 4 hc (via p).
// n-tile for (gate g, sub p) = g*16 + w*4 + p.
// Whh frag class by kt:  kt0 -> VGPR bv[gp]; kt1..4 -> AGPR ba[gp*4+kt-1];
// kt5 -> gp<14 ? VGPR bv[16+gp] : LDS slot gp-14; kt6 -> LDS 2+gp;
// kt7 -> LDS 18+gp.   (34 LDS slots per wave, as in round 1.)
// ---------------------------------------------------------------------------
__global__ __launch_bounds__(256, 1) void rec_kernel(
    const uint32_t* __restrict__ xp, const float* __restrict__ Whh,
    float* __restrict__ c_state, uint16_t* __restrict__ h_state,
    float* __restrict__ out, const float* __restrict__ headW,
    const float* __restrict__ headb, int ct, int tcol0, int do_head) {
  __shared__ short8 B_lds[4 * 34 * 64];   // 139264 B
  __shared__ uint16_t h_lds[2][16][264];  // 16896 B (pad 264 -> <=2-way)
  __shared__ float headbuf[16][64];       // 4096 B   (total 160256 B)

  const int tid = threadIdx.x, w = tid >> 6, l = tid & 63;
  const int l16 = l & 15, lg = l >> 4;
  const int blk = blockIdx.x, b0 = blk * 16;

  // ---- Whh -> bf16 fragments: VGPR / AGPR / LDS (one-time) ----
  short8 ba[64];   // AGPR-resident (4 regs each, 256 AGPRs)
  short8 bv[30];   // VGPR-resident
#pragma unroll
  for (int g = 0; g < 4; ++g)
#pragma unroll
    for (int p = 0; p < 4; ++p) {
      const int gp = g * 4 + p;
      const int nt = g * 16 + w * 4 + p;
#pragma unroll
      for (int kt = 0; kt < 8; ++kt) {
        const float* s = Whh + (size_t)(nt * 16 + l16) * 256 + kt * 32 + lg * 8;
        short8 fr;
#pragma unroll
        for (int e = 0; e < 8; ++e) fr[e] = (short)f2bf(s[e]);
        if (kt == 0) {
          bv[gp] = fr;
        } else if (kt <= 4) {
          asm("" : "+a"(fr));           // pin to AGPR class
          ba[gp * 4 + (kt - 1)] = fr;
        } else if (kt == 5) {
          if (gp < 14) bv[16 + gp] = fr;
          else B_lds[(w * 34 + (gp - 14)) * 64 + l] = fr;
        } else if (kt == 6) {
          B_lds[(w * 34 + 2 + gp) * 64 + l] = fr;
        } else {
          B_lds[(w * 34 + 18 + gp) * 64 + l] = fr;
        }
      }
    }

  // ---- state load ----
  float c_reg[4][4];
#pragma unroll
  for (int p = 0; p < 4; ++p)
#pragma unroll
    for (int j = 0; j < 4; ++j)
      c_reg[p][j] = c_state[(size_t)(b0 + lg * 4 + j) * 256 + w * 64 + p * 16 + l16];
  for (int idx = tid; idx < 16 * 256; idx += 256)
    h_lds[0][idx >> 8][idx & 255] = h_state[(size_t)(b0 + (idx >> 8)) * 256 + (idx & 255)];
  float hw4[4];
#pragma unroll
  for (int p = 0; p < 4; ++p) hw4[p] = headW[w * 64 + p * 16 + l16];
  const float hb = headb[0];

  // ---- xproj prefetch for t=0 ----
  u32x2 xpf[4][4];
#pragma unroll
  for (int g = 0; g < 4; ++g)
#pragma unroll
    for (int p = 0; p < 4; ++p) {
      size_t idx = ((((size_t)0 * 16 + blk) * 64 + (g * 16 + w * 4 + p)) * 64 + l) * 2;
      xpf[g][p] = *(const u32x2*)(xp + idx);
    }

  __syncthreads();

  for (int t = 0; t < ct; ++t) {
    const int cur = t & 1, nxt = cur ^ 1;
    const int tn = (t + 1 < ct) ? t + 1 : t;  // clamped prefetch target
    float hp[4] = {0.f, 0.f, 0.f, 0.f};

#pragma unroll
    for (int p = 0; p < 4; ++p) {
      f32x4 acc[4];
      // kt = 0: builtin, VGPR frags, zero srcC
      {
        short8 a = *(const short8*)(&h_lds[cur][l16][0 * 32 + lg * 8]);
#pragma unroll
        for (int g = 0; g < 4; ++g)
          acc[g] = MFMA(a, bv[g * 4 + p], f32x4{0.f, 0.f, 0.f, 0.f});
      }
      // kt = 1..4: inline-asm MFMA, AGPR frags (mid-chain only)
#pragma unroll
      for (int kt = 1; kt <= 4; ++kt) {
        short8 a = *(const short8*)(&h_lds[cur][l16][kt * 32 + lg * 8]);
#pragma unroll
        for (int g = 0; g < 4; ++g)
          acc[g] = mfma_a(a, ba[(g * 4 + p) * 4 + (kt - 1)], acc[g]);
      }
      // kt = 5: builtin, VGPR (gp<14) or LDS
      {
        short8 a = *(const short8*)(&h_lds[cur][l16][5 * 32 + lg * 8]);
#pragma unroll
        for (int g = 0; g < 4; ++g) {
          const int gp = g * 4 + p;
          if (gp < 14) acc[g] = MFMA(a, bv[16 + gp], acc[g]);
          else acc[g] = MFMA(a, B_lds[(w * 34 + (gp - 14)) * 64 + l], acc[g]);
        }
      }
      // kt = 6,7: builtin, LDS frags
      {
        short8 a = *(const short8*)(&h_lds[cur][l16][6 * 32 + lg * 8]);
#pragma unroll
        for (int g = 0; g < 4; ++g)
          acc[g] = MFMA(a, B_lds[(w * 34 + 2 + (g * 4 + p)) * 64 + l], acc[g]);
      }
      {
        short8 a = *(const short8*)(&h_lds[cur][l16][7 * 32 + lg * 8]);
#pragma unroll
        for (int g = 0; g < 4; ++g)
          acc[g] = MFMA(a, B_lds[(w * 34 + 18 + (g * 4 + p)) * 64 + l], acc[g]);
      }

      // ---- activations (all lane-local), i,f,g,o ----
#pragma unroll
      for (int j = 0; j < 4; ++j) {
        const int hi = j & 1, wd = j >> 1;
        float gi = acc[0][j] + bfhalf(xpf[0][p][wd], hi);
        float gf = acc[1][j] + bfhalf(xpf[1][p][wd], hi);
        float gg = acc[2][j] + bfhalf(xpf[2][p][wd], hi);
        float go = acc[3][j] + bfhalf(xpf[3][p][wd], hi);
        // sig(i)*tanh(g) = (eg-1) / ((1+ei)*(eg+1))
        float ei = ex2(-gi * L2E);
        float eg = ex2(fminf(2.f * gg * L2E, 80.f));
        float sitg = (eg - 1.f) * rcp((1.f + ei) * (eg + 1.f));
        float ef = ex2(-gf * L2E);
        float cc = fmaf(c_reg[p][j], rcp(1.f + ef), sitg);
        c_reg[p][j] = cc;
        float eo = ex2(-go * L2E);
        float ec = ex2(fminf(2.f * cc * L2E, 80.f));
        float hh = (ec - 1.f) * rcp((1.f + eo) * (ec + 1.f));
        hp[j] = fmaf(hh, hw4[p], hp[j]);
        h_lds[nxt][lg * 4 + j][w * 64 + p * 16 + l16] = f2bf(hh);
      }
      // consume-then-prefetch next step's xproj for this p (hidden latency)
#pragma unroll
      for (int g = 0; g < 4; ++g) {
        size_t idx = ((((size_t)tn * 16 + blk) * 64 + (g * 16 + w * 4 + p)) * 64 + l) * 2;
        xpf[g][p] = *(const u32x2*)(xp + idx);
      }
    }

    if (do_head) {
#pragma unroll
      for (int j = 0; j < 4; ++j) headbuf[lg * 4 + j][w * 16 + l16] = hp[j];
      __syncthreads();
      {
        const int b = tid >> 4, i = tid & 15;
        float s = headbuf[b][i] + headbuf[b][16 + i] + headbuf[b][32 + i] + headbuf[b][48 + i];
        s += __shfl_down(s, 8, 16);
        s += __shfl_down(s, 4, 16);
        s += __shfl_down(s, 2, 16);
        s += __shfl_down(s, 1, 16);
        if (i == 0) out[(size_t)(b0 + b) * 91 + (tcol0 + t)] = s + hb;
      }
      __syncthreads();  // headbuf reuse + h_lds[nxt] ready
    } else {
      __syncthreads();
    }
  }

  // ---- state writeback ----
#pragma unroll
  for (int p = 0; p < 4; ++p)
#pragma unroll
    for (int j = 0; j < 4; ++j)
      c_state[(size_t)(b0 + lg * 4 + j) * 256 + w * 64 + p * 16 + l16] = c_reg[p][j];
  for (int idx = tid; idx < 16 * 256; idx += 256)
    h_state[(size_t)(b0 + (idx >> 8)) * 256 + (idx & 255)] = h_lds[ct & 1][idx >> 8][idx & 255];
}

// ---------------------------------------------------------------------------
extern "C" void kernel_launch(void* const* d_in, const int* in_sizes, int n_in,
                              void* d_out, int out_size, void* d_ws, size_t ws_size,
                              hipStream_t stream) {
  const float* headW = (const float*)d_in[12];
  const float* headb = (const float*)d_in[13];
  float* out = (float*)d_out;

  char* ws = (char*)d_ws;
  float* c_state = (float*)ws;                      // 256 KB
  uint16_t* h_state = (uint16_t*)(ws + 262144);     // 128 KB
  uint32_t* xp = (uint32_t*)(ws + 393216);          // chunk buffer, 512 KB per t

  int ct_max = 1;
  if (ws_size > 393216 + 512 * 1024) {
    size_t c = (ws_size - 393216) / (512 * 1024);
    ct_max = (c > 365) ? 365 : (int)c;
  }

  init_kernel<<<256, 256, 0, stream>>>(c_state, h_state, out);

  struct Phase { const float* x; const float* Wih; const float* Whh; const float* b; int T; int D; int head; };
  Phase ph[3] = {
      {(const float*)d_in[0], (const float*)d_in[3], (const float*)d_in[4], (const float*)d_in[5],
       in_sizes[0] / (256 * 64), 64, 0},
      {(const float*)d_in[1], (const float*)d_in[6], (const float*)d_in[7], (const float*)d_in[8],
       in_sizes[1] / (256 * 32), 32, 0},
      {(const float*)d_in[2], (const float*)d_in[9], (const float*)d_in[10], (const float*)d_in[11],
       in_sizes[2] / (256 * 16), 16, 1},
  };

  for (int pi = 0; pi < 3; ++pi) {
    const Phase& P = ph[pi];
    for (int t0 = 0; t0 < P.T; t0 += ct_max) {
      int ct = (P.T - t0 < ct_max) ? (P.T - t0) : ct_max;
      dim3 g(ct * 2);
      if (P.D == 64)
        xproj_kernel<64><<<g, 512, 0, stream>>>(P.x, P.Wih, P.b, xp, t0, P.T);
      else if (P.D == 32)
        xproj_kernel<32><<<g, 512, 0, stream>>>(P.x, P.Wih, P.b, xp, t0, P.T);
      else
        xproj_kernel<16><<<g, 512, 0, stream>>>(P.x, P.Wih, P.b, xp, t0, P.T);
      rec_kernel<<<16, 256, 0, stream>>>(xp, P.Whh, c_state, h_state, out,
                                         headW, headb, ct, t0, P.head);
    }
  }
}

// Round 4
// 1619.866 us; speedup vs baseline: 1.4727x; 1.3623x over previous
//
#include <hip/hip_runtime.h>
#include <stdint.h>

// ============================================================================
// S2S2S LSTM forecaster, MI355X.  Round 4: latency-bound fix.
//   rec_kernel: 16 blocks x 512 thr (8 waves, 2 waves/SIMD). Wave w owns
//   h-cols [32w,32w+32) for all 4 gates. Whh bf16: 46 frags/wave VGPR +
//   18 frags/wave LDS (147 KB). h single-buffered [16][264] in LDS.
//   Per step: 2 lgkmcnt-only barriers (no vmcnt drain -> xp prefetch stays
//   in flight across steps). All MFMAs are builtins.
// Output: cols 0..75 = future-decoder head, 76..90 = 0 (ref overwrites out_f).
// ============================================================================

typedef __attribute__((ext_vector_type(8))) short short8;  // 8 x bf16
typedef __attribute__((ext_vector_type(4))) float f32x4;   // MFMA acc
typedef __attribute__((ext_vector_type(2))) unsigned int u32x2;

#define L2E 1.4426950408889634f

__device__ __forceinline__ uint16_t f2bf(float f) {  // fp32 -> bf16 bits, RNE
  uint32_t x = __float_as_uint(f);
  x += 0x7fffu + ((x >> 16) & 1u);
  return (uint16_t)(x >> 16);
}
__device__ __forceinline__ uint32_t pk2(float a, float b) {
  return (uint32_t)f2bf(a) | ((uint32_t)f2bf(b) << 16);
}
__device__ __forceinline__ float bfhalf(uint32_t w, int hi) {  // bf16 -> fp32
  return __uint_as_float(hi ? (w & 0xffff0000u) : (w << 16));
}
__device__ __forceinline__ f32x4 MFMA(short8 a, short8 b, f32x4 c) {
  return __builtin_amdgcn_mfma_f32_16x16x32_bf16(a, b, c, 0, 0, 0);
}
__device__ __forceinline__ float ex2(float x) { return __builtin_amdgcn_exp2f(x); }
__device__ __forceinline__ float rcp(float x) { return __builtin_amdgcn_rcpf(x); }

// Barrier that waits only LDS ops (lgkmcnt), NOT vmcnt: global prefetch loads
// stay in flight across steps. sched_barriers fence code motion.
__device__ __forceinline__ void lgkm_barrier() {
  __builtin_amdgcn_sched_barrier(0);
  asm volatile("s_waitcnt lgkmcnt(0)" ::: "memory");
  __builtin_amdgcn_s_barrier();
  __builtin_amdgcn_sched_barrier(0);
}

// ---------------------------------------------------------------------------
__global__ void init_kernel(float* c_state, uint16_t* h_state, float* out) {
  int i = blockIdx.x * 256 + threadIdx.x;
  if (i < 65536) { c_state[i] = 0.f; h_state[i] = 0; }
  if (i < 256 * 91) out[i] = 0.f;
}

// ---------------------------------------------------------------------------
// xproj (unchanged, validated): out[t][b][n] = x[b][t]@Wih[n]+bias[n], bf16,
// fragment-permuted: xp[tc][btile][ntile][lane][j] matching MFMA C/D map.
// ---------------------------------------------------------------------------
template <int DIN>
__global__ __launch_bounds__(512) void xproj_kernel(
    const float* __restrict__ x, const float* __restrict__ Wih,
    const float* __restrict__ bias, uint32_t* __restrict__ xp,
    int t0, int T) {
  const int tid = threadIdx.x, w = tid >> 6, l = tid & 63;
  const int l16 = l & 15, lg = l >> 4;
  const int tc = blockIdx.x >> 1;
  const int sub = blockIdx.x & 1;
  const int t = t0 + tc;
  constexpr int KT = (DIN + 31) / 32;

  short8 bfr[8][KT];
  float bv[8];
#pragma unroll
  for (int ni = 0; ni < 8; ++ni) {
    const int n = (w * 8 + ni) * 16 + l16;
    bv[ni] = bias[n];
#pragma unroll
    for (int kt = 0; kt < KT; ++kt) {
      const int k0 = kt * 32 + lg * 8;
      short8 fr;
#pragma unroll
      for (int e = 0; e < 8; ++e) fr[e] = 0;
      if (k0 + 8 <= DIN) {
        const float* s = Wih + (size_t)n * DIN + k0;
#pragma unroll
        for (int e = 0; e < 8; ++e) fr[e] = (short)f2bf(s[e]);
      }
      bfr[ni][kt] = fr;
    }
  }

  for (int mi = 0; mi < 8; ++mi) {
    const int btile = sub * 8 + mi;
    const int b = btile * 16 + l16;
    short8 af[KT];
#pragma unroll
    for (int kt = 0; kt < KT; ++kt) {
      const int k0 = kt * 32 + lg * 8;
      short8 fr;
#pragma unroll
      for (int e = 0; e < 8; ++e) fr[e] = 0;
      if (k0 + 8 <= DIN) {
        const float* s = x + ((size_t)b * T + t) * DIN + k0;
#pragma unroll
        for (int e = 0; e < 8; ++e) fr[e] = (short)f2bf(s[e]);
      }
      af[kt] = fr;
    }
#pragma unroll
    for (int ni = 0; ni < 8; ++ni) {
      f32x4 acc = {0.f, 0.f, 0.f, 0.f};
#pragma unroll
      for (int kt = 0; kt < KT; ++kt) acc = MFMA(af[kt], bfr[ni][kt], acc);
      const int nt = w * 8 + ni;
      size_t idx = ((((size_t)tc * 16 + btile) * 64 + nt) * 64 + l) * 2;
      u32x2 v;
      v[0] = pk2(acc[0] + bv[ni], acc[1] + bv[ni]);
      v[1] = pk2(acc[2] + bv[ni], acc[3] + bv[ni]);
      *(u32x2*)(xp + idx) = v;
    }
  }
}

// ---------------------------------------------------------------------------
// Recurrent kernel: 16 blocks x 512 thr (8 waves, 2 waves/SIMD).
// Wave w: h-cols [32w,32w+32), global 16-col n-tile (g,nt) = g*16 + w*2 + nt.
// Whh frag (g,nt,kt): kt<=5 in VGPR bv[] except (g==3,kt==5) in LDS;
// kt==6 -> LDS slot g*2+nt; kt==7 -> LDS 8+g*2+nt; (g3,kt5) -> LDS 16+nt.
// Reg index: g<3 -> (g*2+nt)*6+kt ; g==3 -> 36+nt*5+kt.
// ---------------------------------------------------------------------------
template <int DO_HEAD>
__global__ __launch_bounds__(512, 2) void rec_kernel(
    const uint32_t* __restrict__ xp, const float* __restrict__ Whh,
    float* __restrict__ c_state, uint16_t* __restrict__ h_state,
    float* __restrict__ out, const float* __restrict__ headW,
    const float* __restrict__ headb, int ct, int tcol0) {
  __shared__ short8 B_lds[8 * 18 * 64];   // 147456 B
  __shared__ uint16_t h_lds[16][264];     // 8448 B (single-buffered)
  __shared__ float headbuf[16][8];        // 512 B   (total 156416 B)

  const int tid = threadIdx.x, w = tid >> 6, l = tid & 63;
  const int l16 = l & 15, lg = l >> 4;
  const int blk = blockIdx.x, b0 = blk * 16;

  // ---- Whh -> bf16 fragments: VGPR / LDS (one-time) ----
  short8 bv[46];
#pragma unroll
  for (int g = 0; g < 4; ++g)
#pragma unroll
    for (int nt = 0; nt < 2; ++nt)
#pragma unroll
      for (int kt = 0; kt < 8; ++kt) {
        const int row = (g * 16 + w * 2 + nt) * 16 + l16;
        const float* s = Whh + (size_t)row * 256 + kt * 32 + lg * 8;
        short8 fr;
#pragma unroll
        for (int e = 0; e < 8; ++e) fr[e] = (short)f2bf(s[e]);
        if (kt == 6) B_lds[(w * 18 + (g * 2 + nt)) * 64 + l] = fr;
        else if (kt == 7) B_lds[(w * 18 + 8 + g * 2 + nt) * 64 + l] = fr;
        else if (kt == 5 && g == 3) B_lds[(w * 18 + 16 + nt) * 64 + l] = fr;
        else bv[(g < 3) ? (g * 2 + nt) * 6 + kt : 36 + nt * 5 + kt] = fr;
      }

  // ---- state load ----
  float c_reg[2][4];
#pragma unroll
  for (int nt = 0; nt < 2; ++nt)
#pragma unroll
    for (int j = 0; j < 4; ++j)
      c_reg[nt][j] = c_state[(size_t)(b0 + lg * 4 + j) * 256 + w * 32 + nt * 16 + l16];
  for (int idx = tid; idx < 16 * 256; idx += 512)
    h_lds[idx >> 8][idx & 255] = h_state[(size_t)(b0 + (idx >> 8)) * 256 + (idx & 255)];
  float hw[2];
#pragma unroll
  for (int nt = 0; nt < 2; ++nt) hw[nt] = headW[w * 32 + nt * 16 + l16];
  const float hb = headb[0];

  // ---- xp prefetch for t=0 ----
  const uint32_t* xpb = xp + ((size_t)(blk * 64 + w * 2) * 64 + l) * 2;
  u32x2 xpf[2][4];
#pragma unroll
  for (int nt = 0; nt < 2; ++nt)
#pragma unroll
    for (int g = 0; g < 4; ++g)
      xpf[nt][g] = *(const u32x2*)(xpb + (size_t)g * 2048 + nt * 128);

  __syncthreads();

  for (int t = 0; t < ct; ++t) {
    const int tn = (t + 1 < ct) ? t + 1 : t;
    uint32_t hpk[2][2];
    float hpj[4] = {0.f, 0.f, 0.f, 0.f};

#pragma unroll
    for (int nt = 0; nt < 2; ++nt) {
      f32x4 acc[4];
      // kt = 0 (VGPR frags, zero srcC)
      {
        short8 a = *(const short8*)(&h_lds[l16][lg * 8]);
#pragma unroll
        for (int g = 0; g < 4; ++g)
          acc[g] = MFMA(a, bv[(g < 3) ? (g * 2 + nt) * 6 : 36 + nt * 5],
                        f32x4{0.f, 0.f, 0.f, 0.f});
      }
      // kt = 1..5 (VGPR frags; g==3,kt==5 from LDS)
#pragma unroll
      for (int kt = 1; kt <= 5; ++kt) {
        short8 a = *(const short8*)(&h_lds[l16][kt * 32 + lg * 8]);
#pragma unroll
        for (int g = 0; g < 4; ++g) {
          if (kt == 5 && g == 3)
            acc[g] = MFMA(a, B_lds[(w * 18 + 16 + nt) * 64 + l], acc[g]);
          else
            acc[g] = MFMA(a, bv[(g < 3) ? (g * 2 + nt) * 6 + kt : 36 + nt * 5 + kt], acc[g]);
        }
      }
      // kt = 6,7 (LDS frags)
#pragma unroll
      for (int kt = 6; kt <= 7; ++kt) {
        short8 a = *(const short8*)(&h_lds[l16][kt * 32 + lg * 8]);
#pragma unroll
        for (int g = 0; g < 4; ++g)
          acc[g] = MFMA(a, B_lds[(w * 18 + (kt - 6) * 8 + g * 2 + nt) * 64 + l], acc[g]);
      }

      // ---- activations (lane-local), gate order i,f,g,o ----
      float hv[4];
#pragma unroll
      for (int j = 0; j < 4; ++j) {
        const int hi = j & 1, wd = j >> 1;
        float gi = acc[0][j] + bfhalf(xpf[nt][0][wd], hi);
        float gf = acc[1][j] + bfhalf(xpf[nt][1][wd], hi);
        float gg = acc[2][j] + bfhalf(xpf[nt][2][wd], hi);
        float go = acc[3][j] + bfhalf(xpf[nt][3][wd], hi);
        float ei = ex2(-gi * L2E);
        float eg = ex2(fminf(2.f * gg * L2E, 80.f));
        float sitg = (eg - 1.f) * rcp((1.f + ei) * (eg + 1.f));
        float ef = ex2(-gf * L2E);
        float cc = fmaf(c_reg[nt][j], rcp(1.f + ef), sitg);
        c_reg[nt][j] = cc;
        float eo = ex2(-go * L2E);
        float ec = ex2(fminf(2.f * cc * L2E, 80.f));
        float hh = (ec - 1.f) * rcp((1.f + eo) * (ec + 1.f));
        if (DO_HEAD) hpj[j] = fmaf(hh, hw[nt], hpj[j]);
        hv[j] = hh;
      }
      hpk[nt][0] = pk2(hv[0], hv[1]);
      hpk[nt][1] = pk2(hv[2], hv[3]);

      // prefetch next step's xp for this nt (vmcnt never drained in loop)
#pragma unroll
      for (int g = 0; g < 4; ++g)
        xpf[nt][g] = *(const u32x2*)(xpb + (size_t)tn * 131072 + g * 2048 + nt * 128);
    }

    lgkm_barrier();  // all waves' h reads complete

#pragma unroll
    for (int nt = 0; nt < 2; ++nt)
#pragma unroll
      for (int j = 0; j < 4; ++j)
        h_lds[lg * 4 + j][w * 32 + nt * 16 + l16] =
            (uint16_t)(hpk[nt][j >> 1] >> ((j & 1) * 16));

    if (DO_HEAD) {
#pragma unroll
      for (int j = 0; j < 4; ++j) {
        float s = hpj[j];
        s += __shfl_xor(s, 8, 16);
        s += __shfl_xor(s, 4, 16);
        s += __shfl_xor(s, 2, 16);
        s += __shfl_xor(s, 1, 16);
        if (l16 == 0) headbuf[lg * 4 + j][w] = s;
      }
    }

    lgkm_barrier();  // h (and headbuf) writes visible

    if (DO_HEAD) {
      if (tid < 16) {
        float s = headbuf[tid][0] + headbuf[tid][1] + headbuf[tid][2] + headbuf[tid][3] +
                  headbuf[tid][4] + headbuf[tid][5] + headbuf[tid][6] + headbuf[tid][7];
        out[(size_t)(b0 + tid) * 91 + (tcol0 + t)] = s + hb;
      }
      lgkm_barrier();  // protect headbuf vs next step's writes
    }
  }

  // ---- state writeback ----
#pragma unroll
  for (int nt = 0; nt < 2; ++nt)
#pragma unroll
    for (int j = 0; j < 4; ++j)
      c_state[(size_t)(b0 + lg * 4 + j) * 256 + w * 32 + nt * 16 + l16] = c_reg[nt][j];
  for (int idx = tid; idx < 16 * 256; idx += 512)
    h_state[(size_t)(b0 + (idx >> 8)) * 256 + (idx & 255)] = h_lds[idx >> 8][idx & 255];
}

// ---------------------------------------------------------------------------
extern "C" void kernel_launch(void* const* d_in, const int* in_sizes, int n_in,
                              void* d_out, int out_size, void* d_ws, size_t ws_size,
                              hipStream_t stream) {
  const float* headW = (const float*)d_in[12];
  const float* headb = (const float*)d_in[13];
  float* out = (float*)d_out;

  char* ws = (char*)d_ws;
  float* c_state = (float*)ws;                      // 256 KB
  uint16_t* h_state = (uint16_t*)(ws + 262144);     // 128 KB
  uint32_t* xp = (uint32_t*)(ws + 393216);          // chunk buffer, 512 KB per t

  int ct_max = 1;
  if (ws_size > 393216 + 512 * 1024) {
    size_t c = (ws_size - 393216) / (512 * 1024);
    ct_max = (c > 365) ? 365 : (int)c;
  }

  init_kernel<<<256, 256, 0, stream>>>(c_state, h_state, out);

  struct Phase { const float* x; const float* Wih; const float* Whh; const float* b; int T; int D; int head; };
  Phase ph[3] = {
      {(const float*)d_in[0], (const float*)d_in[3], (const float*)d_in[4], (const float*)d_in[5],
       in_sizes[0] / (256 * 64), 64, 0},
      {(const float*)d_in[1], (const float*)d_in[6], (const float*)d_in[7], (const float*)d_in[8],
       in_sizes[1] / (256 * 32), 32, 0},
      {(const float*)d_in[2], (const float*)d_in[9], (const float*)d_in[10], (const float*)d_in[11],
       in_sizes[2] / (256 * 16), 16, 1},
  };

  for (int pi = 0; pi < 3; ++pi) {
    const Phase& P = ph[pi];
    for (int t0 = 0; t0 < P.T; t0 += ct_max) {
      int ct = (P.T - t0 < ct_max) ? (P.T - t0) : ct_max;
      dim3 g(ct * 2);
      if (P.D == 64)
        xproj_kernel<64><<<g, 512, 0, stream>>>(P.x, P.Wih, P.b, xp, t0, P.T);
      else if (P.D == 32)
        xproj_kernel<32><<<g, 512, 0, stream>>>(P.x, P.Wih, P.b, xp, t0, P.T);
      else
        xproj_kernel<16><<<g, 512, 0, stream>>>(P.x, P.Wih, P.b, xp, t0, P.T);
      if (P.head)
        rec_kernel<1><<<16, 512, 0, stream>>>(xp, P.Whh, c_state, h_state, out,
                                              headW, headb, ct, t0);
      else
        rec_kernel<0><<<16, 512, 0, stream>>>(xp, P.Whh, c_state, h_state, out,
                                              headW, headb, ct, t0);
    }
  }
}

// Round 5
// 1381.524 us; speedup vs baseline: 1.7268x; 1.1725x over previous
//
#include <hip/hip_runtime.h>
#include <stdint.h>

// ============================================================================
// S2S2S LSTM forecaster, MI355X.  Round 5: transposed MFMA + 1 barrier/step.
//   rec_kernel: 16 blocks x 512 thr (8 waves, 2 waves/SIMD). Transposed
//   compute: gates^T[grow, b] = Whh(A) . h^T(B);  lane = (grow lg*4+j, b l16).
//   h-update: one ds_write_b64 (4 contiguous bf16 cols) + cvt_pk packing.
//   h double-buffered -> ONE lgkm barrier per step (vmcnt never drained).
//   Whh frags: kt0..5 regs (48 frags/wave), kt6..7 LDS (128 KB).
// Output: cols 0..75 = future-decoder head, 76..90 = 0 (ref overwrites out_f).
// ============================================================================

typedef __attribute__((ext_vector_type(8))) short short8;  // 8 x bf16
typedef __attribute__((ext_vector_type(4))) float f32x4;   // MFMA acc
typedef __attribute__((ext_vector_type(2))) unsigned int u32x2;

#define L2E 1.4426950408889634f

__device__ __forceinline__ uint16_t f2bf(float f) {  // fp32 -> bf16 bits, RNE
  uint32_t x = __float_as_uint(f);
  x += 0x7fffu + ((x >> 16) & 1u);
  return (uint16_t)(x >> 16);
}
__device__ __forceinline__ uint32_t pk2(float a, float b) {
  return (uint32_t)f2bf(a) | ((uint32_t)f2bf(b) << 16);
}
__device__ __forceinline__ uint32_t cvtpk(float lo, float hi) {  // 1-inst pack
  uint32_t r;
  asm("v_cvt_pk_bf16_f32 %0, %1, %2" : "=v"(r) : "v"(lo), "v"(hi));
  return r;
}
__device__ __forceinline__ float bfhalf(uint32_t w, int hi) {  // bf16 -> fp32
  return __uint_as_float(hi ? (w & 0xffff0000u) : (w << 16));
}
__device__ __forceinline__ f32x4 MFMA(short8 a, short8 b, f32x4 c) {
  return __builtin_amdgcn_mfma_f32_16x16x32_bf16(a, b, c, 0, 0, 0);
}
__device__ __forceinline__ float ex2(float x) { return __builtin_amdgcn_exp2f(x); }
__device__ __forceinline__ float rcp(float x) { return __builtin_amdgcn_rcpf(x); }

// Barrier waiting only LDS ops (lgkmcnt), NOT vmcnt: xp prefetch loads stay
// in flight across steps. sched_barriers fence code motion.
__device__ __forceinline__ void lgkm_barrier() {
  __builtin_amdgcn_sched_barrier(0);
  asm volatile("s_waitcnt lgkmcnt(0)" ::: "memory");
  __builtin_amdgcn_s_barrier();
  __builtin_amdgcn_sched_barrier(0);
}

// ---------------------------------------------------------------------------
__global__ void init_kernel(float* c_state, uint16_t* h_state, float* out) {
  int i = blockIdx.x * 256 + threadIdx.x;
  if (i < 65536) { c_state[i] = 0.f; h_state[i] = 0; }
  if (i < 256 * 91) out[i] = 0.f;
}

// ---------------------------------------------------------------------------
// xproj (transposed): emits C^T fragments: xp[tc][btile][rowtile][lane][2]
// where lane = (gate-row lg*4+j, batch l16), values bf16-packed (j0,j1)(j2,j3).
// acc = MFMA(Wih_frag(A), x_frag(B)); bias added per gate-row (float4).
// ---------------------------------------------------------------------------
template <int DIN>
__global__ __launch_bounds__(512) void xproj_kernel(
    const float* __restrict__ x, const float* __restrict__ Wih,
    const float* __restrict__ bias, uint32_t* __restrict__ xp,
    int t0, int T) {
  const int tid = threadIdx.x, w = tid >> 6, l = tid & 63;
  const int l16 = l & 15, lg = l >> 4;
  const int tc = blockIdx.x >> 1;
  const int sub = blockIdx.x & 1;
  const int t = t0 + tc;
  constexpr int KT = (DIN + 31) / 32;

  short8 bfr[8][KT];     // Wih fragments (A-operand): row (w*8+ni)*16+l16
  float4 bias4[8];
#pragma unroll
  for (int ni = 0; ni < 8; ++ni) {
    const int n = (w * 8 + ni) * 16 + l16;
    bias4[ni] = *(const float4*)&bias[(w * 8 + ni) * 16 + lg * 4];
#pragma unroll
    for (int kt = 0; kt < KT; ++kt) {
      const int k0 = kt * 32 + lg * 8;
      short8 fr;
#pragma unroll
      for (int e = 0; e < 8; ++e) fr[e] = 0;
      if (k0 + 8 <= DIN) {
        const float* s = Wih + (size_t)n * DIN + k0;
#pragma unroll
        for (int e = 0; e < 8; ++e) fr[e] = (short)f2bf(s[e]);
      }
      bfr[ni][kt] = fr;
    }
  }

  for (int mi = 0; mi < 8; ++mi) {
    const int btile = sub * 8 + mi;
    const int b = btile * 16 + l16;
    short8 af[KT];       // x fragments (B-operand): batch l16, k contiguous
#pragma unroll
    for (int kt = 0; kt < KT; ++kt) {
      const int k0 = kt * 32 + lg * 8;
      short8 fr;
#pragma unroll
      for (int e = 0; e < 8; ++e) fr[e] = 0;
      if (k0 + 8 <= DIN) {
        const float* s = x + ((size_t)b * T + t) * DIN + k0;
#pragma unroll
        for (int e = 0; e < 8; ++e) fr[e] = (short)f2bf(s[e]);
      }
      af[kt] = fr;
    }
#pragma unroll
    for (int ni = 0; ni < 8; ++ni) {
      f32x4 acc = {0.f, 0.f, 0.f, 0.f};
#pragma unroll
      for (int kt = 0; kt < KT; ++kt) acc = MFMA(bfr[ni][kt], af[kt], acc);
      const int nt = w * 8 + ni;
      size_t idx = ((((size_t)tc * 16 + btile) * 64 + nt) * 64 + l) * 2;
      u32x2 v;
      v[0] = pk2(acc[0] + bias4[ni].x, acc[1] + bias4[ni].y);
      v[1] = pk2(acc[2] + bias4[ni].z, acc[3] + bias4[ni].w);
      *(u32x2*)(xp + idx) = v;
    }
  }
}

// ---------------------------------------------------------------------------
// Recurrent kernel: 16 blocks x 512 thr. Wave w owns hidden cols [32w,32w+32)
// (2 row-tiles nt), all 4 gates. Gate-row tile (g,nt) = g*16 + w*2 + nt.
// Transposed: lane = (hidden col (w*2+nt)*16+lg*4+j, batch l16).
// Whh frags: kt<=5 -> bv[(g*2+nt)*6+kt] (48 regs-frags);
//            kt6 -> LDS slot g*2+nt; kt7 -> LDS 8+g*2+nt.
// ---------------------------------------------------------------------------
template <int DO_HEAD>
__global__ __launch_bounds__(512, 2) void rec_kernel(
    const uint32_t* __restrict__ xp, const float* __restrict__ Whh,
    float* __restrict__ c_state, uint16_t* __restrict__ h_state,
    float* __restrict__ out, const float* __restrict__ headW,
    const float* __restrict__ headb, int ct, int tcol0) {
  __shared__ short8 B_lds[8 * 16 * 64];   // 131072 B
  __shared__ uint16_t h_lds[2][16][264];  // 16896 B (double-buffered)
  __shared__ float headbuf[2][16][8];     // 1024 B   (total 148992 B)

  const int tid = threadIdx.x, w = tid >> 6, l = tid & 63;
  const int l16 = l & 15, lg = l >> 4;
  const int blk = blockIdx.x, b0 = blk * 16;

  // ---- Whh -> bf16 fragments: regs (kt0..5) / LDS (kt6,7) ----
  short8 bv[48];
#pragma unroll
  for (int g = 0; g < 4; ++g)
#pragma unroll
    for (int nt = 0; nt < 2; ++nt)
#pragma unroll
      for (int kt = 0; kt < 8; ++kt) {
        const int row = (g * 16 + w * 2 + nt) * 16 + l16;
        const float* s = Whh + (size_t)row * 256 + kt * 32 + lg * 8;
        short8 fr;
#pragma unroll
        for (int e = 0; e < 8; ++e) fr[e] = (short)f2bf(s[e]);
        const int tile = g * 2 + nt;
        if (kt <= 5) bv[tile * 6 + kt] = fr;
        else B_lds[(w * 16 + (kt - 6) * 8 + tile) * 64 + l] = fr;
      }

  // ---- state load (vectorized; lane owns (4 cols x 1 batch) per nt) ----
  float c_reg[2][4];
#pragma unroll
  for (int nt = 0; nt < 2; ++nt) {
    float4 c4 = *(const float4*)&c_state[(size_t)(b0 + l16) * 256 +
                                         (w * 2 + nt) * 16 + lg * 4];
    c_reg[nt][0] = c4.x; c_reg[nt][1] = c4.y;
    c_reg[nt][2] = c4.z; c_reg[nt][3] = c4.w;
  }
  for (int idx = tid; idx < 16 * 256; idx += 512)
    h_lds[0][idx >> 8][idx & 255] = h_state[(size_t)(b0 + (idx >> 8)) * 256 + (idx & 255)];
  float4 hw4[2];
#pragma unroll
  for (int nt = 0; nt < 2; ++nt)
    hw4[nt] = *(const float4*)&headW[(w * 2 + nt) * 16 + lg * 4];
  const float hb = headb[0];

  // ---- xp prefetch for t=0 ----
  const uint32_t* xpb = xp + ((size_t)(blk * 64 + w * 2) * 64 + l) * 2;
  u32x2 xpf[2][4];
#pragma unroll
  for (int nt = 0; nt < 2; ++nt)
#pragma unroll
    for (int g = 0; g < 4; ++g)
      xpf[nt][g] = *(const u32x2*)(xpb + (size_t)g * 2048 + nt * 128);

  __syncthreads();

  for (int t = 0; t < ct; ++t) {
    const int cur = t & 1, nxt = cur ^ 1;
    const int tn = (t + 1 < ct) ? t + 1 : t;
    float hp = 0.f;

#pragma unroll
    for (int nt = 0; nt < 2; ++nt) {
      f32x4 acc[4];
      // kt = 0 (reg frags, zero srcC); A = Whh frag, B = h frag
      {
        short8 hf = *(const short8*)(&h_lds[cur][l16][lg * 8]);
#pragma unroll
        for (int g = 0; g < 4; ++g)
          acc[g] = MFMA(bv[(g * 2 + nt) * 6], hf, f32x4{0.f, 0.f, 0.f, 0.f});
      }
#pragma unroll
      for (int kt = 1; kt <= 5; ++kt) {
        short8 hf = *(const short8*)(&h_lds[cur][l16][kt * 32 + lg * 8]);
#pragma unroll
        for (int g = 0; g < 4; ++g)
          acc[g] = MFMA(bv[(g * 2 + nt) * 6 + kt], hf, acc[g]);
      }
#pragma unroll
      for (int kt = 6; kt <= 7; ++kt) {
        short8 hf = *(const short8*)(&h_lds[cur][l16][kt * 32 + lg * 8]);
#pragma unroll
        for (int g = 0; g < 4; ++g)
          acc[g] = MFMA(B_lds[(w * 16 + (kt - 6) * 8 + g * 2 + nt) * 64 + l], hf, acc[g]);
      }

      // ---- activations (lane-local), gate order i,f,g,o ----
      float hv[4];
#pragma unroll
      for (int j = 0; j < 4; ++j) {
        const int hi = j & 1, wd = j >> 1;
        float gi = acc[0][j] + bfhalf(xpf[nt][0][wd], hi);
        float gf = acc[1][j] + bfhalf(xpf[nt][1][wd], hi);
        float gg = acc[2][j] + bfhalf(xpf[nt][2][wd], hi);
        float go = acc[3][j] + bfhalf(xpf[nt][3][wd], hi);
        float ei = ex2(-gi * L2E);
        float eg = ex2(fminf(2.f * gg * L2E, 80.f));
        float sitg = (eg - 1.f) * rcp((1.f + ei) * (eg + 1.f));
        float ef = ex2(-gf * L2E);
        float cc = fmaf(c_reg[nt][j], rcp(1.f + ef), sitg);
        c_reg[nt][j] = cc;
        float eo = ex2(-go * L2E);
        float ec = ex2(fminf(2.f * cc * L2E, 80.f));
        float hh = (ec - 1.f) * rcp((1.f + eo) * (ec + 1.f));
        hv[j] = hh;
      }
      if (DO_HEAD) {
        hp = fmaf(hv[0], hw4[nt].x, hp); hp = fmaf(hv[1], hw4[nt].y, hp);
        hp = fmaf(hv[2], hw4[nt].z, hp); hp = fmaf(hv[3], hw4[nt].w, hp);
      }
      // packed h write: 4 contiguous bf16 cols -> one b64 store
      {
        u32x2 hwrd;
        hwrd[0] = cvtpk(hv[0], hv[1]);
        hwrd[1] = cvtpk(hv[2], hv[3]);
        *(u32x2*)(&h_lds[nxt][l16][(w * 2 + nt) * 16 + lg * 4]) = hwrd;
      }
      // prefetch next step's xp for this nt (vmcnt never drained in loop)
#pragma unroll
      for (int g = 0; g < 4; ++g)
        xpf[nt][g] = *(const u32x2*)(xpb + (size_t)tn * 131072 + g * 2048 + nt * 128);
    }

    if (DO_HEAD) {
      float s = hp;
      s += __shfl_xor(s, 16);
      s += __shfl_xor(s, 32);
      if (lg == 0) headbuf[t & 1][l16][w] = s;
    }

    lgkm_barrier();  // h[nxt] (and headbuf) visible; all cur-reads done

    if (DO_HEAD) {
      if (tid < 16) {
        const float* hbp = headbuf[t & 1][tid];
        float s = hbp[0] + hbp[1] + hbp[2] + hbp[3] + hbp[4] + hbp[5] + hbp[6] + hbp[7];
        out[(size_t)(b0 + tid) * 91 + (tcol0 + t)] = s + hb;
      }
    }
  }

  // ---- state writeback ----
#pragma unroll
  for (int nt = 0; nt < 2; ++nt) {
    float4 c4 = {c_reg[nt][0], c_reg[nt][1], c_reg[nt][2], c_reg[nt][3]};
    *(float4*)&c_state[(size_t)(b0 + l16) * 256 + (w * 2 + nt) * 16 + lg * 4] = c4;
  }
  for (int idx = tid; idx < 16 * 256; idx += 512)
    h_state[(size_t)(b0 + (idx >> 8)) * 256 + (idx & 255)] = h_lds[ct & 1][idx >> 8][idx & 255];
}

// ---------------------------------------------------------------------------
extern "C" void kernel_launch(void* const* d_in, const int* in_sizes, int n_in,
                              void* d_out, int out_size, void* d_ws, size_t ws_size,
                              hipStream_t stream) {
  const float* headW = (const float*)d_in[12];
  const float* headb = (const float*)d_in[13];
  float* out = (float*)d_out;

  char* ws = (char*)d_ws;
  float* c_state = (float*)ws;                      // 256 KB
  uint16_t* h_state = (uint16_t*)(ws + 262144);     // 128 KB
  uint32_t* xp = (uint32_t*)(ws + 393216);          // chunk buffer, 512 KB per t

  int ct_max = 1;
  if (ws_size > 393216 + 512 * 1024) {
    size_t c = (ws_size - 393216) / (512 * 1024);
    ct_max = (c > 365) ? 365 : (int)c;
  }

  init_kernel<<<256, 256, 0, stream>>>(c_state, h_state, out);

  struct Phase { const float* x; const float* Wih; const float* Whh; const float* b; int T; int D; int head; };
  Phase ph[3] = {
      {(const float*)d_in[0], (const float*)d_in[3], (const float*)d_in[4], (const float*)d_in[5],
       in_sizes[0] / (256 * 64), 64, 0},
      {(const float*)d_in[1], (const float*)d_in[6], (const float*)d_in[7], (const float*)d_in[8],
       in_sizes[1] / (256 * 32), 32, 0},
      {(const float*)d_in[2], (const float*)d_in[9], (const float*)d_in[10], (const float*)d_in[11],
       in_sizes[2] / (256 * 16), 16, 1},
  };

  for (int pi = 0; pi < 3; ++pi) {
    const Phase& P = ph[pi];
    for (int t0 = 0; t0 < P.T; t0 += ct_max) {
      int ct = (P.T - t0 < ct_max) ? (P.T - t0) : ct_max;
      dim3 g(ct * 2);
      if (P.D == 64)
        xproj_kernel<64><<<g, 512, 0, stream>>>(P.x, P.Wih, P.b, xp, t0, P.T);
      else if (P.D == 32)
        xproj_kernel<32><<<g, 512, 0, stream>>>(P.x, P.Wih, P.b, xp, t0, P.T);
      else
        xproj_kernel<16><<<g, 512, 0, stream>>>(P.x, P.Wih, P.b, xp, t0, P.T);
      if (P.head)
        rec_kernel<1><<<16, 512, 0, stream>>>(xp, P.Whh, c_state, h_state, out,
                                              headW, headb, ct, t0);
      else
        rec_kernel<0><<<16, 512, 0, stream>>>(xp, P.Whh, c_state, h_state, out,
                                              headW, headb, ct, t0);
    }
  }
}